// Round 13
// baseline (235.233 us; speedup 1.0000x reference)
//
#include <hip/hip_runtime.h>
#include <hip/hip_bf16.h>

// ---------------------------------------------------------------------------
// QuantumImageEncoder R13: R12 (dword-safe MFMA conv2 — fixed the R3-R6
// corruption; absmax landed 0.0234 vs 0.02 from bf16 rounding) with staging
// dtype switched bf16 -> fp16 (11-bit mantissa, ~8x less rounding error;
// activations O(1-5) & weights O(0.3) are far from fp16 range limits).
// MFMA: __builtin_amdgcn_mfma_f32_16x16x32_f16 (same shape/fragments).
// Register-only alpha/gamma probes gate MFMA; fp16-VALU fallback otherwise.
// prep/fc/quantum = R11 verbatim (passing).
// ---------------------------------------------------------------------------

#define B_EPS 1e-5f

typedef __attribute__((ext_vector_type(8))) _Float16 half8; // 8 fp16 (4 VGPRs)
typedef __attribute__((ext_vector_type(4))) float f32x4;    // MFMA acc

__device__ inline unsigned pack2h(float lo, float hi) {     // [lo | hi<<16] fp16
    _Float16 l = (_Float16)lo, h = (_Float16)hi;
    return (unsigned)__builtin_bit_cast(unsigned short, l) |
           ((unsigned)__builtin_bit_cast(unsigned short, h) << 16);
}

// ---------------- prep: build U (block 0, zero stats) + wT2 reformat --------
__global__ void prep_kernel(const float* __restrict__ rl,
                            const float* __restrict__ f1w,
                            float* __restrict__ Uout,
                            float* __restrict__ wT2,
                            float* __restrict__ stats)
{
    if (blockIdx.x == 0) {
        __shared__ float2 U[16][16];
        int t = threadIdx.x;
        int r = t >> 4, cc = t & 15;
        U[r][cc] = (r == cc) ? make_float2(1.f, 0.f) : make_float2(0.f, 0.f);
        stats[t] = 0.f;
        stats[t + 256] = 0.f;
        __syncthreads();
        for (int op = 0; op < 30; op++) {
            int kind = op & 3;
            float2 cur = U[r][cc];
            float2 nv;
            if (kind == 3) {
                float2 part = U[r ^ 8][cc];
                nv = (r & 1) ? part : cur;
            } else {
                int m = 8 >> kind;
                float theta = rl[op - (op >> 2)];
                float ch = cosf(0.5f * theta), sh = sinf(0.5f * theta);
                float2 part = U[r ^ m][cc];
                int br = (r & m) ? 1 : 0;
                float2 gc, gp;
                if (kind == 0)      { gc = make_float2(ch, 0.f);           gp = make_float2(0.f, -sh); }
                else if (kind == 1) { gc = make_float2(ch, 0.f);           gp = make_float2(br ? sh : -sh, 0.f); }
                else                { gc = make_float2(ch, br ? sh : -sh); gp = make_float2(0.f, 0.f); }
                nv.x = gc.x*cur.x - gc.y*cur.y + gp.x*part.x - gp.y*part.y;
                nv.y = gc.x*cur.y + gc.y*cur.x + gp.x*part.y + gp.y*part.x;
            }
            __syncthreads();
            U[r][cc] = nv;
            __syncthreads();
        }
        ((float2*)Uout)[t] = U[r][cc];
    } else {
        int id = (blockIdx.x - 1) * 256 + threadIdx.x;
        if (id < 784 * 64) {
            int k = id >> 6, o = id & 63;
            wT2[(((k >> 2) * 64 + o) << 2) + (k & 3)] = f1w[o * 784 + k];
        }
    }
}

// ---------------- conv backbone + fused fc: 2 samples / block, 4 waves ------
__global__ __launch_bounds__(256) void conv_kernel(
    const float* __restrict__ x,  const float* __restrict__ c1w,
    const float* __restrict__ c1b, const float* __restrict__ c2w,
    const float* __restrict__ c2b, const float* __restrict__ wT2,
    const float* __restrict__ f1b, const float* __restrict__ f2w,
    const float* __restrict__ f2bias, float* __restrict__ feat,
    float* __restrict__ stats)
{
    // U1: xin (phase A) | { p1c fp16, flat } (phase B+)
    __shared__ union alignas(16) {
        float xin[2][30 * 32];                       // 15360 B
        struct {
            _Float16 p1c[2][288 * 8];                // 9216 B  (16x18 halo'd, ch-last)
            float flat[2][784];                      // 6272 B
        } b;
    } u;
    // U2: p1 fp32 (conv1 out) | c2out fp32 (one sample) | fc scratch
    __shared__ union alignas(16) {
        float p1[2][8 * 292];                        // 18688 B
        float c2out[196 * 16];                       // 12544 B (per-sample)
        struct { float part[4][64]; float hs[2][64]; } fc;
    } v;
    __shared__ unsigned w2c[12 * 16 * 4];            // [tap][ch][ci2] packed fp16
    __shared__ float w1s[8][9], b1s[8], b2s[16];

    int t = threadIdx.x;
    int w = t >> 6, lane = t & 63;

    // ---- P1: zero xin + p1, stage conv weights (w2c as packed uints)
    {
        float4 z = make_float4(0.f, 0.f, 0.f, 0.f);
        float4* xz = (float4*)u.xin;
        for (int i = t; i < 2 * 30 * 32 / 4; i += 256) xz[i] = z;
        float4* pz = (float4*)v.p1;
        for (int i = t; i < 2 * 8 * 292 / 4; i += 256) pz[i] = z;
    }
    if (t < 72) ((float*)w1s)[t] = c1w[t];
    if (t < 8)  b1s[t] = c1b[t];
    if (t >= 8 && t < 24) b2s[t - 8] = c2b[t - 8];
    for (int j = t; j < 576; j += 256) {             // taps 0..8 packed
        int tap = j >> 6, r = j & 63, ch = r >> 2, ci2 = r & 3;
        float lo = c2w[ch * 72 + (2 * ci2) * 9 + tap];
        float hi = c2w[ch * 72 + (2 * ci2 + 1) * 9 + tap];
        w2c[(tap * 16 + ch) * 4 + ci2] = pack2h(lo, hi);
    }
    if (t < 192) w2c[576 + t] = 0u;                  // taps 9..11 zero
    {
        const float4* xg = (const float4*)(x + (size_t)blockIdx.x * 2 * 784);
        for (int i = t; i < 392; i += 256) {
            float4 vv4 = xg[i];
            int s = i / 196, q = (i - s * 196) * 4;
            float vv[4] = {vv4.x, vv4.y, vv4.z, vv4.w};
            #pragma unroll
            for (int j = 0; j < 4; j++) {
                int p = q + j, rr = p / 28, cc = p - rr * 28;
                u.xin[s][(rr + 1) * 32 + cc + 1] = vv[j];
            }
        }
    }
    __syncthreads();

    // ---- P2: conv1 + relu + pool -> v.p1 (R11 verbatim)
    {
        int s = w >> 1, h = w & 1;
        int c = lane >> 3, g = lane & 7;
        if (g < 7) {
            float wk[9];
            #pragma unroll
            for (int q = 0; q < 9; q++) wk[q] = w1s[c][q];
            float bias = b1s[c];
            const float* xb = &u.xin[s][4 * g];
            float* pout = &v.p1[s][c * 292];
            for (int ii = 0; ii < 7; ii++) {
                int i = h * 7 + ii;
                const float* r = xb + 2 * i * 32;
                float rv[4][6];
                #pragma unroll
                for (int dr = 0; dr < 4; dr++) {
                    float2 a = *(const float2*)(r + dr * 32);
                    float2 b = *(const float2*)(r + dr * 32 + 2);
                    float2 c2v = *(const float2*)(r + dr * 32 + 4);
                    rv[dr][0] = a.x;  rv[dr][1] = a.y;
                    rv[dr][2] = b.x;  rv[dr][3] = b.y;
                    rv[dr][4] = c2v.x; rv[dr][5] = c2v.y;
                }
                float o[2][4];
                #pragma unroll
                for (int dr = 0; dr < 2; dr++)
                    #pragma unroll
                    for (int j = 0; j < 4; j++) {
                        float acc = bias;
                        #pragma unroll
                        for (int ky = 0; ky < 3; ky++)
                            #pragma unroll
                            for (int kx = 0; kx < 3; kx++)
                                acc = fmaf(wk[ky * 3 + kx], rv[dr + ky][j + kx], acc);
                        o[dr][j] = acc;
                    }
                #pragma unroll
                for (int jj = 0; jj < 2; jj++) {
                    float m = fmaxf(fmaxf(o[0][2 * jj], o[0][2 * jj + 1]),
                                    fmaxf(o[1][2 * jj], o[1][2 * jj + 1]));
                    pout[(i + 1) * 18 + 1 + 2 * g + jj] = fmaxf(m, 0.f);
                }
            }
        }
    }
    __syncthreads();   // xin dead; p1 complete

    // ---- P3: repack p1 fp32 -> p1c fp16 channel-last (FULL-DWORD writes)
    {
        unsigned* pc = (unsigned*)u.b.p1c;           // 2304 dwords total
        for (int i = t; i < 2304; i += 256) {
            int s = i / 1152, r = i - 1152 * s;
            int pix = r >> 2, c2 = r & 3;            // pix in [0,288)
            float lo = v.p1[s][(2 * c2) * 292 + pix];
            float hi = v.p1[s][(2 * c2 + 1) * 292 + pix];
            pc[i] = pack2h(lo, hi);
        }
    }
    __syncthreads();   // p1 dead after this point (c2out may overwrite)

    // ---- P4: register-only MFMA layout probes (R6 method, fp16)
    int q = lane >> 4, n = lane & 15;
    int okm, alpha[4], gamma[4];
    {
        const _Float16 one = (_Float16)1.0f;
        const _Float16 enc = (_Float16)(float)(n + 1);   // exact, 1..16
        const half8 z8 = {0,0,0,0,0,0,0,0};
        const f32x4 z4 = {0.f, 0.f, 0.f, 0.f};
        half8 aa, bb;
        f32x4 Pa, Pb, Pc, Pd, Pe, Pf;
        aa = z8; bb = z8; if (q == 0) { aa[0] = enc; bb[0] = one; }
        Pa = __builtin_amdgcn_mfma_f32_16x16x32_f16(aa, bb, z4, 0, 0, 0);
        aa = z8; bb = z8; if (q == 0) { aa[5] = enc; bb[5] = one; }
        Pb = __builtin_amdgcn_mfma_f32_16x16x32_f16(aa, bb, z4, 0, 0, 0);
        aa = z8; bb = z8; if (q == 2) { aa[6] = enc; bb[6] = one; }
        Pe = __builtin_amdgcn_mfma_f32_16x16x32_f16(aa, bb, z4, 0, 0, 0);
        aa = z8; bb = z8; if (q == 3) { aa[3] = enc; bb[3] = one; }
        Pf = __builtin_amdgcn_mfma_f32_16x16x32_f16(aa, bb, z4, 0, 0, 0);
        aa = z8; bb = z8; if (q == 0) { aa[0] = one; bb[0] = enc; }
        Pc = __builtin_amdgcn_mfma_f32_16x16x32_f16(aa, bb, z4, 0, 0, 0);
        aa = z8; bb = z8; if (q == 1) { aa[1] = one; bb[1] = enc; }
        Pd = __builtin_amdgcn_mfma_f32_16x16x32_f16(aa, bb, z4, 0, 0, 0);
        int ok = 1;
        #pragma unroll
        for (int e = 0; e < 4; e++) {
            int a1 = (int)(Pa[e] + 0.5f);
            int g1 = (int)(Pc[e] + 0.5f);
            ok &= (a1 >= 1) & (a1 <= 16) & (g1 >= 1) & (g1 <= 16);
            ok &= (fabsf(Pb[e] - Pa[e]) < 0.5f) & (fabsf(Pe[e] - Pa[e]) < 0.5f)
                & (fabsf(Pf[e] - Pa[e]) < 0.5f) & (fabsf(Pd[e] - Pc[e]) < 0.5f);
            alpha[e] = a1 - 1;
            gamma[e] = g1 - 1;
        }
        okm = __all(ok);
    }

    // ---- P4b: conv2 per sample (MFMA or fallback) -> c2out, then pool
    for (int s = 0; s < 2; s++) {
        if (okm) {
            half8 bfr[3];
            int atoff[3];
            #pragma unroll
            for (int s2 = 0; s2 < 3; s2++) {
                int tap = 4 * s2 + q;
                bfr[s2] = *(const half8*)&w2c[(tap * 16 + n) * 4];
                atoff[s2] = (tap < 9) ? ((tap / 3) * 18 + (tap % 3)) * 8 : 0;
            }
            for (int tau = w; tau < 13; tau += 4) {
                int r0 = tau * 16 + n;
                int rp = r0 < 196 ? r0 : 0;
                int oy = rp / 14, ox = rp - 14 * oy;
                const _Float16* ab = &u.b.p1c[s][(oy * 18 + ox) * 8];
                f32x4 acc = {0.f, 0.f, 0.f, 0.f};
                acc = __builtin_amdgcn_mfma_f32_16x16x32_f16(*(const half8*)(ab + atoff[0]), bfr[0], acc, 0, 0, 0);
                acc = __builtin_amdgcn_mfma_f32_16x16x32_f16(*(const half8*)(ab + atoff[1]), bfr[1], acc, 0, 0, 0);
                acc = __builtin_amdgcn_mfma_f32_16x16x32_f16(*(const half8*)(ab + atoff[2]), bfr[2], acc, 0, 0, 0);
                #pragma unroll
                for (int e = 0; e < 4; e++) {
                    int pix = tau * 16 + alpha[e];
                    if (pix < 196) v.c2out[pix * 16 + gamma[e]] = acc[e];
                }
            }
        } else {
            // VALU fallback (fp16 staged data, correct staging)
            for (int idx = t; idx < 3136; idx += 256) {
                int pix = idx >> 4, ch = idx & 15;
                int oy = pix / 14, ox = pix - 14 * oy;
                float acc = 0.f;
                #pragma unroll
                for (int tap = 0; tap < 9; tap++) {
                    const half8 av = *(const half8*)&u.b.p1c[s][((oy + tap / 3) * 18 + ox + tap % 3) * 8];
                    const half8 wv = *(const half8*)&w2c[(tap * 16 + ch) * 4];
                    #pragma unroll
                    for (int j = 0; j < 8; j++)
                        acc = fmaf((float)av[j], (float)wv[j], acc);
                }
                v.c2out[pix * 16 + ch] = acc;
            }
        }
        __syncthreads();
        // ---- pool(2x2) + bias + relu -> u.b.flat[s]
        for (int idx = t; idx < 784; idx += 256) {
            int ch = idx / 49, g = idx - 49 * ch;
            int gy = g / 7, gx = g - 7 * gy;
            const float* cb = &v.c2out[((2 * gy) * 14 + 2 * gx) * 16 + ch];
            float v0 = cb[0], v1 = cb[16];
            float v2 = cb[224], v3 = cb[240];
            float m = fmaxf(fmaxf(v0, v1), fmaxf(v2, v3));
            u.b.flat[s][idx] = fmaxf(m + b2s[ch], 0.f);
        }
        __syncthreads();
    }

    // ---- P5: fc1 partials (R11 verbatim; scratch in v.fc)
    {
        int s = w >> 1, h2 = w & 1;
        const float* fl = u.b.flat[s];
        const float4* wp4 = (const float4*)wT2 + lane;
        int g0 = h2 * 98;
        float a0 = 0.f, a1 = 0.f;
        #pragma unroll 2
        for (int g = g0; g < g0 + 98; g += 2) {
            float4 wv0 = wp4[(size_t)g * 64];
            float4 f0 = *(const float4*)&fl[4 * g];
            float4 wv1 = wp4[(size_t)(g + 1) * 64];
            float4 f1 = *(const float4*)&fl[4 * (g + 1)];
            a0 = fmaf(f0.x, wv0.x, fmaf(f0.y, wv0.y, fmaf(f0.z, wv0.z, fmaf(f0.w, wv0.w, a0))));
            a1 = fmaf(f1.x, wv1.x, fmaf(f1.y, wv1.y, fmaf(f1.z, wv1.z, fmaf(f1.w, wv1.w, a1))));
        }
        v.fc.part[w][lane] = a0 + a1;
    }
    __syncthreads();

    // ---- P6: combine halves + bias + relu
    if (t < 128) {
        int s = t >> 6, o = t & 63;
        float h = v.fc.part[2 * s][o] + v.fc.part[2 * s + 1][o] + f1b[o];
        v.fc.hs[s][o] = fmaxf(h, 0.f);
    }
    __syncthreads();

    // ---- P7: fc2 + feat + sharded BN stats
    if (t < 8) {
        int s = t >> 2, j = t & 3;
        float a = f2bias[j];
        #pragma unroll
        for (int o = 0; o < 64; o++) a = fmaf(v.fc.hs[s][o], f2w[j * 64 + o], a);
        feat[((size_t)blockIdx.x * 2 + s) * 4 + j] = a;
        int g = blockIdx.x & 63;
        atomicAdd(&stats[g * 8 + j], a);
        atomicAdd(&stats[g * 8 + 4 + j], a * a);
    }
}

// ---------------- BN + encoder + U matvec + PauliZ measure ------------------
__global__ __launch_bounds__(128) void quantum_kernel(
    const float* __restrict__ feat, const float* __restrict__ Ug,
    const float* __restrict__ stats, const float* __restrict__ bn_g,
    const float* __restrict__ bn_b, float* __restrict__ out, int B)
{
    __shared__ float2 Us[256];
    __shared__ float sm[8];
    int t = threadIdx.x;
    for (int i = t; i < 256; i += 128) Us[i] = ((const float2*)Ug)[i];
    if (t < 8) sm[t] = 0.f;
    __syncthreads();
    {
        float v = stats[t] + stats[t + 128] + stats[t + 256] + stats[t + 384];
        atomicAdd(&sm[t & 7], v);
    }
    __syncthreads();
    int s = blockIdx.x * 128 + t;
    float4 fv = ((const float4*)feat)[s];
    float f[4] = {fv.x, fv.y, fv.z, fv.w};
    float cn[4], sn[4];
    float invB = 1.0f / (float)B;
    #pragma unroll
    for (int w = 0; w < 4; w++) {
        float mean = sm[w] * invB;
        float var  = sm[4 + w] * invB - mean * mean;
        float fh = (f[w] - mean) / sqrtf(var + B_EPS) * bn_g[w] + bn_b[w];
        cn[w] = cosf(0.5f * fh);
        sn[w] = sinf(0.5f * fh);
    }
    float re0[16], im0[16];
    #pragma unroll
    for (int k = 0; k < 16; k++) {
        float mag = ((k & 8) ? sn[0] : cn[0]) * ((k & 4) ? sn[1] : cn[1]) *
                    ((k & 2) ? sn[2] : cn[2]) * ((k & 1) ? sn[3] : cn[3]);
        int m = __popc(k) & 3;
        re0[k] = (m == 0) ? mag : (m == 2) ? -mag : 0.f;
        im0[k] = (m == 1) ? -mag : (m == 3) ? mag : 0.f;
    }
    float o0 = 0.f, o1 = 0.f, o2 = 0.f, o3 = 0.f;
    #pragma unroll
    for (int r = 0; r < 16; r++) {
        float ar = 0.f, ai = 0.f;
        #pragma unroll
        for (int k = 0; k < 16; k++) {
            float2 uu = Us[r * 16 + k];
            ar += uu.x * re0[k] - uu.y * im0[k];
            ai += uu.x * im0[k] + uu.y * re0[k];
        }
        float p = ar * ar + ai * ai;
        o0 += (r & 8) ? -p : p;
        o1 += (r & 4) ? -p : p;
        o2 += (r & 2) ? -p : p;
        o3 += (r & 1) ? -p : p;
    }
    float4 ov = {o0, o1, o2, o3};
    ((float4*)out)[s] = ov;
}

// ---------------------------------------------------------------------------
extern "C" void kernel_launch(void* const* d_in, const int* in_sizes, int n_in,
                              void* d_out, int out_size, void* d_ws, size_t ws_size,
                              hipStream_t stream)
{
    const float* x   = (const float*)d_in[0];
    const float* c1w = (const float*)d_in[1];
    const float* c1b = (const float*)d_in[2];
    const float* c2w = (const float*)d_in[3];
    const float* c2b = (const float*)d_in[4];
    const float* f1w = (const float*)d_in[5];
    const float* f1b = (const float*)d_in[6];
    const float* f2w = (const float*)d_in[7];
    const float* f2b = (const float*)d_in[8];
    const float* bng = (const float*)d_in[9];
    const float* bnb = (const float*)d_in[10];
    const float* rl  = (const float*)d_in[11];
    float* out = (float*)d_out;

    int B = in_sizes[0] / 784;

    float* wsf   = (float*)d_ws;
    float* feat  = wsf;                          // B*4
    float* wT2   = feat + (size_t)B * 4;         // 784*64 (as [k4][64][4])
    float* U     = wT2 + 784 * 64;               // 512 (float2[256])
    float* stats = U + 512;                      // 512 (64 shards x 8)

    prep_kernel<<<197, 256, 0, stream>>>(rl, f1w, U, wT2, stats);
    conv_kernel<<<B / 2, 256, 0, stream>>>(x, c1w, c1b, c2w, c2b, wT2,
                                           f1b, f2w, f2b, feat, stats);
    quantum_kernel<<<B / 128, 128, 0, stream>>>(feat, U, stats, bng, bnb, out, B);
}